// Round 4
// baseline (516.407 us; speedup 1.0000x reference)
//
#include <hip/hip_runtime.h>
#include <hip/hip_cooperative_groups.h>

namespace cg = cooperative_groups;

#define DIM   4096
#define KVDIM 1024   // n_kv_heads * head_dim
#define NB    8      // batch
#define TOTAL 16384
#define NBLK  1024   // 4 blocks/CU on 256 CUs -> co-resident for grid.sync

typedef float fvec4 __attribute__((ext_vector_type(4)));   // clang-native, nt-store OK

// One fused kernel:
//  phase 1: x[b,j] = dot(emb[b,:], W_up[j,:])          (8192 wave-dots)
//  phase 2: y[b,o] = dot(val[b,:], W_down[o,:])        (4096 wave-dots, 8 b each)
//           val[b,k] = x[b, (k>>9)*128 + (k&127)]      (repeat-interleave gather)
//  phase 3: out[row,:] = y[seq_id(row),:]              (256 MB stream, nt stores)
__global__ __launch_bounds__(256, 4)
void fused_pca(const float* __restrict__ emb, const float* __restrict__ wup,
               const float* __restrict__ wdn, const int* __restrict__ seqlen,
               float* __restrict__ x, float* __restrict__ y,
               float* __restrict__ out) {
    cg::grid_group grid = cg::this_grid();
    const int lane = threadIdx.x & 63;
    const int wid  = blockIdx.x * 4 + (threadIdx.x >> 6);   // 0..4095

    // ---- phase 1: up-projection, 2 dots per wave ----
    #pragma unroll
    for (int i = 0; i < 2; i++) {
        int d = wid * 2 + i;           // 0..8191
        int j = d >> 3;                // 0..1023
        int b = d & 7;
        const fvec4* e = (const fvec4*)(emb + b * DIM);
        const fvec4* w = (const fvec4*)(wup + (long)j * DIM);
        float acc = 0.f;
        #pragma unroll
        for (int it = lane; it < DIM / 4; it += 64) {
            fvec4 ev = e[it], wv = w[it];
            fvec4 p = ev * wv;
            acc += p.x + p.y + p.z + p.w;
        }
        #pragma unroll
        for (int off = 32; off; off >>= 1) acc += __shfl_down(acc, off, 64);
        if (lane == 0) x[b * KVDIM + j] = acc;
    }

    grid.sync();

    // ---- phase 2: down-projection, one o per wave, all 8 batches ----
    {
        int o = wid;                   // 0..4095
        const fvec4* w = (const fvec4*)(wdn + (long)o * DIM);
        float acc[NB];
        #pragma unroll
        for (int b = 0; b < NB; b++) acc[b] = 0.f;
        for (int it = lane; it < DIM / 4; it += 64) {
            int k0 = it * 4;
            int kv = ((k0 >> 9) << 7) + (k0 & 127);   // 16B-aligned (k0 % 4 == 0)
            fvec4 wv = w[it];
            #pragma unroll
            for (int b = 0; b < NB; b++) {
                const fvec4 xv = *(const fvec4*)(x + b * KVDIM + kv);
                fvec4 p = xv * wv;
                acc[b] += p.x + p.y + p.z + p.w;
            }
        }
        #pragma unroll
        for (int b = 0; b < NB; b++) {
            #pragma unroll
            for (int off = 32; off; off >>= 1) acc[b] += __shfl_down(acc[b], off, 64);
            if (lane == 0) y[b * DIM + o] = acc[b];
        }
    }

    grid.sync();

    // ---- phase 3: ragged broadcast, 16 rows per block ----
    int c0 = seqlen[0];
    int c1 = c0 + seqlen[1];
    int c2 = c1 + seqlen[2];
    int c3 = c2 + seqlen[3];
    int c4 = c3 + seqlen[4];
    int c5 = c4 + seqlen[5];
    int c6 = c5 + seqlen[6];
    for (int g = 0; g < TOTAL / NBLK; g++) {
        int row = blockIdx.x + g * NBLK;
        int s = (row >= c0) + (row >= c1) + (row >= c2) + (row >= c3)
              + (row >= c4) + (row >= c5) + (row >= c6);
        const fvec4* yr = (const fvec4*)(y + s * DIM);
        fvec4* orow = (fvec4*)(out + (long)row * DIM);
        #pragma unroll
        for (int c = threadIdx.x; c < DIM / 4; c += 256) {
            fvec4 v = yr[c];
            __builtin_nontemporal_store(v, orow + c);
        }
    }
}

extern "C" void kernel_launch(void* const* d_in, const int* in_sizes, int n_in,
                              void* d_out, int out_size, void* d_ws, size_t ws_size,
                              hipStream_t stream) {
    const float* emb = (const float*)d_in[0];
    const float* wup = (const float*)d_in[1];
    const float* wdn = (const float*)d_in[2];
    const int* seqlen = (const int*)d_in[3];

    float* x = (float*)d_ws;           // 8*1024 fp32 = 32 KB
    float* y = x + NB * KVDIM;         // 8*4096 fp32 = 128 KB
    float* out = (float*)d_out;

    void* args[] = {(void*)&emb, (void*)&wup, (void*)&wdn, (void*)&seqlen,
                    (void*)&x, (void*)&y, (void*)&out};
    (void)hipLaunchCooperativeKernel((const void*)fused_pca, dim3(NBLK), dim3(256),
                                     args, 0, stream);
}

// Round 5
// 358.344 us; speedup vs baseline: 1.4411x; 1.4411x over previous
//
#include <hip/hip_runtime.h>

#define DIM   4096
#define KVDIM 1024   // n_kv_heads * head_dim
#define NB    8      // batch
#define TOTAL 16384
#define BCAST_BLOCKS 4096   // 4 rows per block

// x[b*KVDIM + j] = dot(emb[b,:], W_up[j,:])  -- one wave per (j,b)
__global__ __launch_bounds__(256)
void k_up(const float* __restrict__ emb, const float* __restrict__ wup,
          float* __restrict__ x) {
    int wid  = blockIdx.x * 4 + (threadIdx.x >> 6);
    int lane = threadIdx.x & 63;
    int j = wid >> 3;      // 0..1023 (b inner: 8 consecutive waves share one W_up row via L2)
    int b = wid & 7;
    const float4* e = (const float4*)(emb + b * DIM);
    const float4* w = (const float4*)(wup + (long)j * DIM);
    float acc = 0.f;
    #pragma unroll
    for (int it = lane; it < DIM / 4; it += 64) {
        float4 ev = e[it], wv = w[it];
        acc += ev.x * wv.x + ev.y * wv.y + ev.z * wv.z + ev.w * wv.w;
    }
    #pragma unroll
    for (int off = 32; off; off >>= 1) acc += __shfl_down(acc, off, 64);
    if (lane == 0) x[b * KVDIM + j] = acc;
}

// y[b*DIM + o] = dot(val[b,:], W_down[o,:]),  val[b,k] = x[b,(k>>9)*128 + (k&127)]
// One wave per o, all 8 batches -> W_down fetched exactly once (64 MB).
__global__ __launch_bounds__(256)
void k_down(const float* __restrict__ x, const float* __restrict__ wdn,
            float* __restrict__ y) {
    int o    = blockIdx.x * 4 + (threadIdx.x >> 6);   // 0..4095
    int lane = threadIdx.x & 63;
    const float4* w = (const float4*)(wdn + (long)o * DIM);
    float acc[NB];
    #pragma unroll
    for (int b = 0; b < NB; b++) acc[b] = 0.f;
    for (int it = lane; it < DIM / 4; it += 64) {
        int k0 = it * 4;
        int kv = ((k0 >> 9) << 7) + (k0 & 127);   // 16B-aligned gather (k0 % 4 == 0)
        float4 wv = w[it];
        #pragma unroll
        for (int b = 0; b < NB; b++) {
            const float4 xv = *(const float4*)(x + b * KVDIM + kv);
            acc[b] += xv.x * wv.x + xv.y * wv.y + xv.z * wv.z + xv.w * wv.w;
        }
    }
    #pragma unroll
    for (int b = 0; b < NB; b++) {
        #pragma unroll
        for (int off = 32; off; off >>= 1) acc[b] += __shfl_down(acc[b], off, 64);
        if (lane == 0) y[b * DIM + o] = acc[b];
    }
}

// out[row,:] = y[seq_id(row),:]  -- plain float4 stores (L2 write-combining),
// 4 rows per block, rows strided by gridDim for even CU load.
__global__ __launch_bounds__(256)
void k_bcast(const float* __restrict__ y, const int* __restrict__ seqlen,
             float4* __restrict__ out) {
    int c0 = seqlen[0];
    int c1 = c0 + seqlen[1];
    int c2 = c1 + seqlen[2];
    int c3 = c2 + seqlen[3];
    int c4 = c3 + seqlen[4];
    int c5 = c4 + seqlen[5];
    int c6 = c5 + seqlen[6];
    #pragma unroll
    for (int g = 0; g < TOTAL / BCAST_BLOCKS; g++) {
        int row = blockIdx.x + g * BCAST_BLOCKS;
        int s = (row >= c0) + (row >= c1) + (row >= c2) + (row >= c3)
              + (row >= c4) + (row >= c5) + (row >= c6);
        const float4* yr = (const float4*)(y + s * DIM);
        float4* orow = out + (long)row * (DIM / 4);
        #pragma unroll
        for (int c = threadIdx.x; c < DIM / 4; c += 256)
            orow[c] = yr[c];
    }
}

extern "C" void kernel_launch(void* const* d_in, const int* in_sizes, int n_in,
                              void* d_out, int out_size, void* d_ws, size_t ws_size,
                              hipStream_t stream) {
    const float* emb = (const float*)d_in[0];
    const float* wup = (const float*)d_in[1];
    const float* wdn = (const float*)d_in[2];
    const int* seqlen = (const int*)d_in[3];

    float* x = (float*)d_ws;           // 8*1024 fp32 = 32 KB
    float* y = x + NB * KVDIM;         // 8*4096 fp32 = 128 KB

    k_up   <<<NB * KVDIM / 4, 256, 0, stream>>>(emb, wup, x);
    k_down <<<DIM / 4,        256, 0, stream>>>(x, wdn, y);
    k_bcast<<<BCAST_BLOCKS,   256, 0, stream>>>(y, seqlen, (float4*)d_out);
}

// Round 6
// 347.967 us; speedup vs baseline: 1.4841x; 1.0298x over previous
//
#include <hip/hip_runtime.h>

#define DIM   4096
#define KVDIM 1024   // n_kv_heads * head_dim
#define NB    8      // batch
#define TOTAL 16384
#define BCAST_BLOCKS 4096   // 4 rows per block

// x[b*KVDIM + j] = dot(emb[b,:], W_up[j,:])  -- one wave per (j,b), fully unrolled
__global__ __launch_bounds__(256)
void k_up(const float* __restrict__ emb, const float* __restrict__ wup,
          float* __restrict__ x) {
    int wid  = blockIdx.x * 4 + (threadIdx.x >> 6);
    int lane = threadIdx.x & 63;
    int j = wid >> 3;      // 0..1023 (b inner: 8 consecutive waves share one W_up row via L2)
    int b = wid & 7;
    const float4* e = (const float4*)(emb + b * DIM);
    const float4* w = (const float4*)(wup + (long)j * DIM);
    float acc = 0.f;
    #pragma unroll
    for (int ii = 0; ii < DIM / 4 / 64; ii++) {   // 16 iterations, compile-time
        int it = ii * 64 + lane;
        float4 ev = e[it], wv = w[it];
        acc += ev.x * wv.x + ev.y * wv.y + ev.z * wv.z + ev.w * wv.w;
    }
    #pragma unroll
    for (int off = 32; off; off >>= 1) acc += __shfl_down(acc, off, 64);
    if (lane == 0) x[b * KVDIM + j] = acc;
}

// y[b*DIM + o] = dot(val[b,:], W_down[o,:]),  val[b,k] = x[b,(k>>9)*128 + (k&127)]
// One o per block; K split across the 4 waves (W_down row still fetched once);
// trip count 4, fully unrolled; LDS reduce across waves.
__global__ __launch_bounds__(256)
void k_down(const float* __restrict__ x, const float* __restrict__ wdn,
            float* __restrict__ y) {
    __shared__ float part[4][NB];
    int o    = blockIdx.x;            // 0..4095
    int wv   = threadIdx.x >> 6;      // 0..3 : K-quarter
    int lane = threadIdx.x & 63;
    const float4* w = (const float4*)(wdn + (long)o * DIM);
    float acc[NB];
    #pragma unroll
    for (int b = 0; b < NB; b++) acc[b] = 0.f;
    #pragma unroll
    for (int ii = 0; ii < 4; ii++) {
        int it = wv * 256 + ii * 64 + lane;       // float4 index into W_down row
        int k0 = it * 4;
        int kv = ((k0 >> 9) << 7) + (k0 & 127);   // 16B-aligned repeat-interleave gather
        float4 wvv = w[it];
        #pragma unroll
        for (int b = 0; b < NB; b++) {
            const float4 xv = *(const float4*)(x + b * KVDIM + kv);
            acc[b] += xv.x * wvv.x + xv.y * wvv.y + xv.z * wvv.z + xv.w * wvv.w;
        }
    }
    #pragma unroll
    for (int b = 0; b < NB; b++) {
        #pragma unroll
        for (int off = 32; off; off >>= 1) acc[b] += __shfl_down(acc[b], off, 64);
    }
    if (lane == 0) {
        #pragma unroll
        for (int b = 0; b < NB; b++) part[wv][b] = acc[b];
    }
    __syncthreads();
    if (threadIdx.x < NB) {
        int b = threadIdx.x;
        float s = part[0][b] + part[1][b] + part[2][b] + part[3][b];
        y[b * DIM + o] = s;
    }
}

// out[row,:] = y[seq_id(row),:]  -- plain float4 stores, 4 rows per block.
__global__ __launch_bounds__(256)
void k_bcast(const float* __restrict__ y, const int* __restrict__ seqlen,
             float4* __restrict__ out) {
    int c0 = seqlen[0];
    int c1 = c0 + seqlen[1];
    int c2 = c1 + seqlen[2];
    int c3 = c2 + seqlen[3];
    int c4 = c3 + seqlen[4];
    int c5 = c4 + seqlen[5];
    int c6 = c5 + seqlen[6];
    #pragma unroll
    for (int g = 0; g < TOTAL / BCAST_BLOCKS; g++) {
        int row = blockIdx.x + g * BCAST_BLOCKS;
        int s = (row >= c0) + (row >= c1) + (row >= c2) + (row >= c3)
              + (row >= c4) + (row >= c5) + (row >= c6);
        const float4* yr = (const float4*)(y + s * DIM);
        float4* orow = out + (long)row * (DIM / 4);
        #pragma unroll
        for (int c = threadIdx.x; c < DIM / 4; c += 256)
            orow[c] = yr[c];
    }
}

extern "C" void kernel_launch(void* const* d_in, const int* in_sizes, int n_in,
                              void* d_out, int out_size, void* d_ws, size_t ws_size,
                              hipStream_t stream) {
    const float* emb = (const float*)d_in[0];
    const float* wup = (const float*)d_in[1];
    const float* wdn = (const float*)d_in[2];
    const int* seqlen = (const int*)d_in[3];

    float* x = (float*)d_ws;           // 8*1024 fp32 = 32 KB
    float* y = x + NB * KVDIM;         // 8*4096 fp32 = 128 KB

    k_up   <<<NB * KVDIM / 4, 256, 0, stream>>>(emb, wup, x);
    k_down <<<DIM,            256, 0, stream>>>(x, wdn, y);
    k_bcast<<<BCAST_BLOCKS,   256, 0, stream>>>(y, seqlen, (float4*)d_out);
}